// Round 15
// baseline (256.046 us; speedup 1.0000x reference)
//
#include <hip/hip_runtime.h>
#include <hip/hip_bf16.h>
#include <hip/hip_fp16.h>
#include <stdint.h>

#define SLOPE 0.2f
#define EPSV 1e-16f
#define LOG2E 1.44269504f
#define H1W 72    // h1p row stride in u32 words: 64 f16x2 words + 8 fp32 a_src (scaled)
#define H2W 36    // 32 f16x2 words + 1 fp32 a_src + 3 pad

#define NPB2  256   // nodes per bucket; bucket = dst >> 8
#define NBLK  512   // count/place blocks (pbh row width)

typedef __attribute__((ext_vector_type(8))) short bf16x8;
typedef __attribute__((ext_vector_type(4))) float f32x4;

static __device__ __forceinline__ uint32_t cvtpk(float a, float b) {   // bf16 pack (weights)
    uint32_t r;
    asm("v_cvt_pk_bf16_f32 %0, %1, %2" : "=v"(r) : "v"(a), "v"(b));
    return r;
}
static __device__ __forceinline__ float lof(uint32_t u) { return __uint_as_float(u << 16); }
static __device__ __forceinline__ float hif(uint32_t u) { return __uint_as_float(u & 0xffff0000u); }

static __device__ __forceinline__ uint32_t pkf16(float a, float b) {   // fp16 pack (RTZ)
    auto r = __builtin_amdgcn_cvt_pkrtz(a, b);
    return __builtin_bit_cast(uint32_t, r);
}

// acc += fp16(lo/hi half of h2) * w   — single VOP3P v_fma_mix_f32
static __device__ __forceinline__ void fmix_lo(float& acc, uint32_t h2, float w) {
    asm("v_fma_mix_f32 %0, %1, %2, %0 op_sel_hi:[1,0,0]" : "+v"(acc) : "v"(h2), "v"(w));
}
static __device__ __forceinline__ void fmix_hi(float& acc, uint32_t h2, float w) {
    asm("v_fma_mix_f32 %0, %1, %2, %0 op_sel:[1,0,0] op_sel_hi:[1,0,0]" : "+v"(acc) : "v"(h2), "v"(w));
}

union FragCvt { uint4 u; bf16x8 f; };

// ================== FUSED: s_count (blocks < nCnt) + gemm1 (blocks >= nCnt) ==================
// gemm1 stages W1 f32 -> bf16 hi/lo inline (no prep kernel, no ordering hazard).
__global__ __launch_bounds__(256) void fused_count_gemm1(
    const int* __restrict__ ei, int* __restrict__ pbh, int E, int NB, int chunk,
    const float* __restrict__ x, const float* __restrict__ W1,
    const float* __restrict__ att_src, const float* __restrict__ att_dst,
    uint32_t* __restrict__ h1p, float* __restrict__ ad1, int N, int nCnt)
{
    __shared__ uint32_t lds[2][128 * 36];   // 36 KB; s_count reuses front as hist[512]
    const int t = threadIdx.x;

    if (blockIdx.x < nCnt) {
        int* hist = (int*)&lds[0][0];
        hist[t] = 0; hist[t + 256] = 0;
        __syncthreads();
        int e0 = blockIdx.x * chunk, e1 = min(E, e0 + chunk);
        for (int e = e0 + t; e < e1; e += 256)
            atomicAdd(&hist[ei[E + e] >> 8], 1);
        __syncthreads();
        for (int b = t; b < NB; b += 256)
            pbh[(size_t)b * NBLK + blockIdx.x] = hist[b];   // bucket-major
        return;
    }

    const int bx = blockIdx.x - nCnt;
    const int w = t >> 6, l = t & 63;
    const int cl = l & 15, rg = l >> 4;
    const int rowbase = bx * 128 + w * 32;

    f32x4 zero = {0.f, 0.f, 0.f, 0.f};
    f32x4 acc[2][8];
    #pragma unroll
    for (int rt = 0; rt < 2; ++rt)
        #pragma unroll
        for (int tl = 0; tl < 8; ++tl) acc[rt][tl] = zero;

    for (int kh = 0; kh < 2; ++kh) {
        if (kh) __syncthreads();
        // stage W1 K-half: 128 cols x 32 k-pairs, f32 -> bf16 hi/lo inline
        for (int i = t; i < 4096; i += 256) {
            int col = i & 127, kp = i >> 7;               // kp 0..31 within half
            int k0 = 2 * (kh * 32 + kp);
            float w0 = W1[(size_t)k0 * 128 + col];
            float w1 = W1[(size_t)(k0 + 1) * 128 + col];
            uint32_t h = cvtpk(w0, w1);
            lds[0][col * 36 + kp] = h;
            lds[1][col * 36 + kp] = cvtpk(w0 - lof(h), w1 - hif(h));
        }
        __syncthreads();
        #pragma unroll
        for (int ks = 0; ks < 2; ++ks) {
            const int kg = kh * 64 + ks * 32 + rg * 8;
            bf16x8 ahi[2], alo[2];
            #pragma unroll
            for (int rt = 0; rt < 2; ++rt) {
                int row = rowbase + rt * 16 + cl;
                row = min(row, N - 1);
                const float* xr = x + (size_t)row * 128 + kg;
                float4 v0 = *(const float4*)xr;
                float4 v1 = *(const float4*)(xr + 4);
                uint32_t h0 = cvtpk(v0.x, v0.y), h1 = cvtpk(v0.z, v0.w);
                uint32_t h2 = cvtpk(v1.x, v1.y), h3 = cvtpk(v1.z, v1.w);
                uint32_t l0 = cvtpk(v0.x - lof(h0), v0.y - hif(h0));
                uint32_t l1 = cvtpk(v0.z - lof(h1), v0.w - hif(h1));
                uint32_t l2 = cvtpk(v1.x - lof(h2), v1.y - hif(h2));
                uint32_t l3 = cvtpk(v1.z - lof(h3), v1.w - hif(h3));
                FragCvt ch, clo;
                ch.u  = make_uint4(h0, h1, h2, h3);
                clo.u = make_uint4(l0, l1, l2, l3);
                ahi[rt] = ch.f; alo[rt] = clo.f;
            }
            #pragma unroll
            for (int tl = 0; tl < 8; ++tl) {
                const int off = (tl * 16 + cl) * 36 + ks * 16 + rg * 4;
                bf16x8 bhi = *(const bf16x8*)&lds[0][off];
                bf16x8 blo = *(const bf16x8*)&lds[1][off];
                #pragma unroll
                for (int rt = 0; rt < 2; ++rt) {
                    acc[rt][tl] = __builtin_amdgcn_mfma_f32_16x16x32_bf16(alo[rt], bhi, acc[rt][tl], 0, 0, 0);
                    acc[rt][tl] = __builtin_amdgcn_mfma_f32_16x16x32_bf16(ahi[rt], blo, acc[rt][tl], 0, 0, 0);
                    acc[rt][tl] = __builtin_amdgcn_mfma_f32_16x16x32_bf16(ahi[rt], bhi, acc[rt][tl], 0, 0, 0);
                }
            }
        }
    }

    // epilogue: fp16 pack; a_s/a_d dots pre-scaled by log2e (exp2-direct downstream)
    #pragma unroll
    for (int rt = 0; rt < 2; ++rt) {
        const int rowb = rowbase + rt * 16 + rg * 4;
        #pragma unroll
        for (int tl = 0; tl < 8; ++tl) {
            f32x4 a = acc[rt][tl];
            float as_ = att_src[tl * 16 + cl] * LOG2E, ad_ = att_dst[tl * 16 + cl] * LOG2E;
            float s0 = a.x * as_, s1 = a.y * as_, s2 = a.z * as_, s3 = a.w * as_;
            float d0 = a.x * ad_, d1 = a.y * ad_, d2 = a.z * ad_, d3 = a.w * ad_;
            #pragma unroll
            for (int off = 1; off < 16; off <<= 1) {
                s0 += __shfl_xor(s0, off); s1 += __shfl_xor(s1, off);
                s2 += __shfl_xor(s2, off); s3 += __shfl_xor(s3, off);
                d0 += __shfl_xor(d0, off); d1 += __shfl_xor(d1, off);
                d2 += __shfl_xor(d2, off); d3 += __shfl_xor(d3, off);
            }
            float av[4] = {a.x, a.y, a.z, a.w};
            #pragma unroll
            for (int r = 0; r < 4; ++r) {
                float partner = __shfl_xor(av[r], 1);
                if (!(cl & 1)) {
                    int row = rowb + r;
                    if (row < N)
                        h1p[(size_t)row * H1W + tl * 8 + (cl >> 1)] = pkf16(av[r], partner);
                }
            }
            if (cl == 0) {
                float sv[4] = {s0, s1, s2, s3}, dv[4] = {d0, d1, d2, d3};
                #pragma unroll
                for (int r = 0; r < 4; ++r) {
                    int row = rowb + r;
                    if (row < N) {
                        h1p[(size_t)row * H1W + 64 + tl] = __float_as_uint(sv[r]);
                        ad1[row * 8 + tl] = dv[r];
                    }
                }
            }
        }
    }
}

// ---------------- GEMM2 (MFMA split-precision, inline W2 conversion) ----------------
__global__ __launch_bounds__(256) void gemm2_mfma(
    const float* __restrict__ h, const float* __restrict__ W2,
    const float* __restrict__ att_src, const float* __restrict__ att_dst,
    uint32_t* __restrict__ h2p, float* __restrict__ ad2, int N)
{
    __shared__ uint32_t lds[2][64 * 36];
    const int t = threadIdx.x;
    const int w = t >> 6, l = t & 63;
    const int cl = l & 15, rg = l >> 4;
    const int rowbase = blockIdx.x * 128 + w * 32;

    f32x4 zero = {0.f, 0.f, 0.f, 0.f};
    f32x4 acc[2][4];
    #pragma unroll
    for (int rt = 0; rt < 2; ++rt)
        #pragma unroll
        for (int tl = 0; tl < 4; ++tl) acc[rt][tl] = zero;

    for (int kh = 0; kh < 2; ++kh) {
        if (kh) __syncthreads();
        for (int i = t; i < 2048; i += 256) {
            int col = i & 63, kp = i >> 6;                // kp 0..31 within half
            int k0 = 2 * (kh * 32 + kp);
            float w0 = W2[(size_t)k0 * 64 + col];
            float w1 = W2[(size_t)(k0 + 1) * 64 + col];
            uint32_t hh = cvtpk(w0, w1);
            lds[0][col * 36 + kp] = hh;
            lds[1][col * 36 + kp] = cvtpk(w0 - lof(hh), w1 - hif(hh));
        }
        __syncthreads();
        #pragma unroll
        for (int ks = 0; ks < 2; ++ks) {
            const int kg = kh * 64 + ks * 32 + rg * 8;
            bf16x8 ahi[2], alo[2];
            #pragma unroll
            for (int rt = 0; rt < 2; ++rt) {
                int row = rowbase + rt * 16 + cl;
                row = min(row, N - 1);
                const float* xr = h + (size_t)row * 128 + kg;
                float4 v0 = *(const float4*)xr;
                float4 v1 = *(const float4*)(xr + 4);
                uint32_t h0 = cvtpk(v0.x, v0.y), h1 = cvtpk(v0.z, v0.w);
                uint32_t h2 = cvtpk(v1.x, v1.y), h3 = cvtpk(v1.z, v1.w);
                uint32_t l0 = cvtpk(v0.x - lof(h0), v0.y - hif(h0));
                uint32_t l1 = cvtpk(v0.z - lof(h1), v0.w - hif(h1));
                uint32_t l2 = cvtpk(v1.x - lof(h2), v1.y - hif(h2));
                uint32_t l3 = cvtpk(v1.z - lof(h3), v1.w - hif(h3));
                FragCvt ch, clo;
                ch.u  = make_uint4(h0, h1, h2, h3);
                clo.u = make_uint4(l0, l1, l2, l3);
                ahi[rt] = ch.f; alo[rt] = clo.f;
            }
            #pragma unroll
            for (int tl = 0; tl < 4; ++tl) {
                const int off = (tl * 16 + cl) * 36 + ks * 16 + rg * 4;
                bf16x8 bhi = *(const bf16x8*)&lds[0][off];
                bf16x8 blo = *(const bf16x8*)&lds[1][off];
                #pragma unroll
                for (int rt = 0; rt < 2; ++rt) {
                    acc[rt][tl] = __builtin_amdgcn_mfma_f32_16x16x32_bf16(alo[rt], bhi, acc[rt][tl], 0, 0, 0);
                    acc[rt][tl] = __builtin_amdgcn_mfma_f32_16x16x32_bf16(ahi[rt], blo, acc[rt][tl], 0, 0, 0);
                    acc[rt][tl] = __builtin_amdgcn_mfma_f32_16x16x32_bf16(ahi[rt], bhi, acc[rt][tl], 0, 0, 0);
                }
            }
        }
    }

    #pragma unroll
    for (int rt = 0; rt < 2; ++rt) {
        const int rowb = rowbase + rt * 16 + rg * 4;
        float s0 = 0.f, s1 = 0.f, s2 = 0.f, s3 = 0.f;
        float d0 = 0.f, d1 = 0.f, d2 = 0.f, d3 = 0.f;
        #pragma unroll
        for (int tl = 0; tl < 4; ++tl) {
            f32x4 a = acc[rt][tl];
            float as_ = att_src[tl * 16 + cl] * LOG2E, ad_ = att_dst[tl * 16 + cl] * LOG2E;
            s0 += a.x * as_; s1 += a.y * as_; s2 += a.z * as_; s3 += a.w * as_;
            d0 += a.x * ad_; d1 += a.y * ad_; d2 += a.z * ad_; d3 += a.w * ad_;
            float av[4] = {a.x, a.y, a.z, a.w};
            #pragma unroll
            for (int r = 0; r < 4; ++r) {
                float partner = __shfl_xor(av[r], 1);
                if (!(cl & 1)) {
                    int row = rowb + r;
                    if (row < N)
                        h2p[(size_t)row * H2W + tl * 8 + (cl >> 1)] = pkf16(av[r], partner);
                }
            }
        }
        #pragma unroll
        for (int off = 1; off < 16; off <<= 1) {
            s0 += __shfl_xor(s0, off); s1 += __shfl_xor(s1, off);
            s2 += __shfl_xor(s2, off); s3 += __shfl_xor(s3, off);
            d0 += __shfl_xor(d0, off); d1 += __shfl_xor(d1, off);
            d2 += __shfl_xor(d2, off); d3 += __shfl_xor(d3, off);
        }
        if (cl == 0) {
            float sv[4] = {s0, s1, s2, s3}, dv[4] = {d0, d1, d2, d3};
            #pragma unroll
            for (int r = 0; r < 4; ++r) {
                int row = rowb + r;
                if (row < N) {
                    h2p[(size_t)row * H2W + 32] = __float_as_uint(sv[r]);
                    ad2[row] = dv[r];
                }
            }
        }
    }
}

// s_scanA: grid NB x 256; bucket totals
__global__ __launch_bounds__(256) void s_scanA(
    const int* __restrict__ pbh, int* __restrict__ btot, int NB)
{
    __shared__ int red[256];
    int b = blockIdx.x, t = threadIdx.x;
    int s = pbh[(size_t)b * NBLK + t] + pbh[(size_t)b * NBLK + 256 + t];
    red[t] = s; __syncthreads();
    for (int off = 128; off; off >>= 1) {
        if (t < off) red[t] += red[t + off];
        __syncthreads();
    }
    if (t == 0) btot[b] = red[0];
}

// s_scanC: grid NB x 256; redundant btot scan for base + per-bucket row scan
__global__ __launch_bounds__(256) void s_scanC(
    int* __restrict__ pbh, const int* __restrict__ btot,
    int* __restrict__ bucket_base, int NB, int E)
{
    __shared__ int ps[256];
    __shared__ int exv[512];
    int b = blockIdx.x, t = threadIdx.x;
    int v0 = (2 * t     < NB) ? btot[2 * t]     : 0;
    int v1 = (2 * t + 1 < NB) ? btot[2 * t + 1] : 0;
    int p = v0 + v1;
    ps[t] = p; __syncthreads();
    for (int off = 1; off < 256; off <<= 1) {
        int add = (t >= off) ? ps[t - off] : 0;
        __syncthreads();
        ps[t] += add;
        __syncthreads();
    }
    int pex = ps[t] - p;
    exv[2 * t] = pex; exv[2 * t + 1] = pex + v0;
    __syncthreads();
    int base = exv[b];
    if (t == 0) {
        bucket_base[b] = base;
        if (b == NB - 1) bucket_base[NB] = E;
    }
    __syncthreads();
    int w0 = pbh[(size_t)b * NBLK + 2 * t], w1 = pbh[(size_t)b * NBLK + 2 * t + 1];
    int pp = w0 + w1;
    ps[t] = pp; __syncthreads();
    for (int off = 1; off < 256; off <<= 1) {
        int add = (t >= off) ? ps[t - off] : 0;
        __syncthreads();
        ps[t] += add;
        __syncthreads();
    }
    int ex = base + ps[t] - pp;
    pbh[(size_t)b * NBLK + 2 * t]     = ex;
    pbh[(size_t)b * NBLK + 2 * t + 1] = ex + w0;
}

// s_place: grid NBLK x 256; place edges into bucket regions (packed src|dst_local)
__global__ __launch_bounds__(256) void s_place(
    const int* __restrict__ ei, const int* __restrict__ pbh,
    uint32_t* __restrict__ staging, int E, int NB, int chunk)
{
    __shared__ int lcur[512];
    int t = threadIdx.x;
    if (t < NB)       lcur[t]       = pbh[(size_t)t * NBLK + blockIdx.x];
    if (t + 256 < NB) lcur[t + 256] = pbh[(size_t)(t + 256) * NBLK + blockIdx.x];
    __syncthreads();
    int e0 = blockIdx.x * chunk, e1 = min(E, e0 + chunk);
    for (int e = e0 + t; e < e1; e += 256) {
        int s = ei[e], d = ei[E + e];
        int p = atomicAdd(&lcur[d >> 8], 1);     // LDS atomic
        staging[p] = ((uint32_t)s << 8) | (uint32_t)(d & 255);
    }
}

// s_build: grid NB x 256; per-bucket CSR build (row_start + sorted_src)
__global__ __launch_bounds__(256) void s_build(
    const uint32_t* __restrict__ staging, const int* __restrict__ bucket_base,
    int* __restrict__ row_start, int* __restrict__ sorted_src, int N, int E, int NB)
{
    __shared__ int cnt[256];
    __shared__ int ofs[256];
    __shared__ int ps[256];
    int b = blockIdx.x, t = threadIdx.x;
    int base = bucket_base[b], end = bucket_base[b + 1];
    cnt[t] = 0;
    __syncthreads();
    for (int i = base + t; i < end; i += 256)
        atomicAdd(&cnt[staging[i] & 255], 1);
    __syncthreads();
    int c = cnt[t];
    ps[t] = c; __syncthreads();
    for (int off = 1; off < 256; off <<= 1) {
        int add = (t >= off) ? ps[t - off] : 0;
        __syncthreads();
        ps[t] += add;
        __syncthreads();
    }
    int ex = ps[t] - c;
    ofs[t] = ex;
    int node = b * NPB2 + t;
    if (node < N) row_start[node] = base + ex;
    if (b == NB - 1 && t == 0) row_start[N] = E;
    __syncthreads();
    for (int i = base + t; i < end; i += 256) {
        uint32_t v = staging[i];
        int pos = base + atomicAdd(&ofs[v & 255], 1);   // LDS atomic
        sorted_src[pos] = (int)(v >> 8);
    }
}

// ---------------- gather layer 1: 64 lanes/node, fp16 rows, 16B gathers, fma_mix,
// row loads software-pipelined one 8-edge group ahead ----------------
__global__ __launch_bounds__(256) void gather1_kernel(
    const int* __restrict__ row_start, const int* __restrict__ sorted_src,
    const float* __restrict__ ad1, const uint32_t* __restrict__ h1p,
    const float* __restrict__ b1, float* __restrict__ hbuf, int N)
{
    int node = blockIdx.x * 4 + (threadIdx.x >> 6);
    if (node >= N) return;
    const int l  = threadIdx.x & 63;
    const int wh = l & 7;          // weight-duty head
    const int eA = l >> 3;         // weight-duty edge slot (0..7)
    const int c8 = l & 15;         // channel-octet: channels 8*c8..+7
    const int q  = l >> 4;         // phase-B quarter (0..3)
    const int hB = c8 >> 1;        // fma-duty head

    int r0 = row_start[node], r1 = row_start[node + 1];

    if (r0 == r1) {                // isolated node: out = elu(b1)
        if (l < 16) {
            #pragma unroll
            for (int g = 0; g < 2; ++g) {
                float4 bv = *(const float4*)&b1[c8 * 8 + g * 4];
                bv.x = bv.x > 0.f ? bv.x : expm1f(bv.x);
                bv.y = bv.y > 0.f ? bv.y : expm1f(bv.y);
                bv.z = bv.z > 0.f ? bv.z : expm1f(bv.z);
                bv.w = bv.w > 0.f ? bv.w : expm1f(bv.w);
                *(float4*)&hbuf[(size_t)node * 128 + c8 * 8 + g * 4] = bv;
            }
        }
        return;
    }

    float adw = ad1[node * 8 + wh];
    const uint32_t* rowp = h1p + 4 * c8;
    float acc[8] = {0.f, 0.f, 0.f, 0.f, 0.f, 0.f, 0.f, 0.f};
    float den = 0.f;

    int jw = r0 + eA;
    int sw0 = sorted_src[jw < r1 ? jw : r0] * H1W;
    int j1 = r0 + 8 + eA;
    int sw1 = sorted_src[j1 < r1 ? j1 : r0] * H1W;
    float av0 = __uint_as_float(h1p[sw0 + 64 + wh]);

    // preload group 0's channel rows
    int of0A = __shfl(sw0,  q      * 8, 64);
    int of1A = __shfl(sw0, (q + 4) * 8, 64);
    uint4 hA0 = *(const uint4*)(rowp + of0A);
    uint4 hA1 = *(const uint4*)(rowp + of1A);

    for (int j = r0; j < r1; j += 8) {
        int jn = j + 16 + eA;
        int swn = sorted_src[jn < r1 ? jn : r0] * H1W;
        float avn = __uint_as_float(h1p[sw1 + 64 + wh]);

        int of0B = __shfl(sw1,  q      * 8, 64);
        int of1B = __shfl(sw1, (q + 4) * 8, 64);
        uint4 hB0 = *(const uint4*)(rowp + of0B);
        uint4 hB1 = *(const uint4*)(rowp + of1B);

        float ev = av0 + adw;
        ev = ev > 0.f ? ev : SLOPE * ev;
        float w = (j + eA) < r1 ? exp2f(ev) : 0.f;
        den += w;

        float wk0 = __shfl(w,  q      * 8 + hB, 64);
        float wk1 = __shfl(w, (q + 4) * 8 + hB, 64);
        fmix_lo(acc[0], hA0.x, wk0); fmix_hi(acc[1], hA0.x, wk0);
        fmix_lo(acc[2], hA0.y, wk0); fmix_hi(acc[3], hA0.y, wk0);
        fmix_lo(acc[4], hA0.z, wk0); fmix_hi(acc[5], hA0.z, wk0);
        fmix_lo(acc[6], hA0.w, wk0); fmix_hi(acc[7], hA0.w, wk0);
        fmix_lo(acc[0], hA1.x, wk1); fmix_hi(acc[1], hA1.x, wk1);
        fmix_lo(acc[2], hA1.y, wk1); fmix_hi(acc[3], hA1.y, wk1);
        fmix_lo(acc[4], hA1.z, wk1); fmix_hi(acc[5], hA1.z, wk1);
        fmix_lo(acc[6], hA1.w, wk1); fmix_hi(acc[7], hA1.w, wk1);

        hA0 = hB0; hA1 = hB1;
        sw0 = sw1; sw1 = swn; av0 = avn;
    }

    den += __shfl_xor(den, 8, 64);
    den += __shfl_xor(den, 16, 64);
    den += __shfl_xor(den, 32, 64);
    float dB = __shfl(den, hB, 64);

    #pragma unroll
    for (int i = 0; i < 8; ++i) {
        acc[i] += __shfl_xor(acc[i], 16, 64);
        acc[i] += __shfl_xor(acc[i], 32, 64);
    }

    if (l < 16) {
        float inv = 1.0f / (dB + EPSV);
        #pragma unroll
        for (int g = 0; g < 2; ++g) {
            float4 bv = *(const float4*)&b1[c8 * 8 + g * 4];
            float v0 = acc[g * 4 + 0] * inv + bv.x;
            float v1 = acc[g * 4 + 1] * inv + bv.y;
            float v2 = acc[g * 4 + 2] * inv + bv.z;
            float v3 = acc[g * 4 + 3] * inv + bv.w;
            v0 = v0 > 0.f ? v0 : expm1f(v0);
            v1 = v1 > 0.f ? v1 : expm1f(v1);
            v2 = v2 > 0.f ? v2 : expm1f(v2);
            v3 = v3 > 0.f ? v3 : expm1f(v3);
            *(float4*)&hbuf[(size_t)node * 128 + c8 * 8 + g * 4] = make_float4(v0, v1, v2, v3);
        }
    }
}

// ---------------- gather layer 2: 32 lanes/node, fp16 rows, 16B gathers, fma_mix,
// row loads pipelined one group ahead ----------------
__global__ __launch_bounds__(256) void gather2_kernel(
    const int* __restrict__ row_start, const int* __restrict__ sorted_src,
    const float* __restrict__ ad2, const uint32_t* __restrict__ h2p,
    const float* __restrict__ b2, float* __restrict__ out, int N)
{
    int node = blockIdx.x * 8 + (threadIdx.x >> 5);
    if (node >= N) return;
    const int l  = threadIdx.x & 31;
    const int eA = l & 7;          // weight-duty edge slot (4x redundant)
    const int c8 = l & 7;          // channel-octet: channels 8*c8..+7
    const int q  = l >> 3;         // phase-B quarter (0..3)

    int r0 = row_start[node], r1 = row_start[node + 1];

    if (r0 == r1) {
        if (l < 8) {
            #pragma unroll
            for (int g = 0; g < 2; ++g) {
                float4 bv = *(const float4*)&b2[c8 * 8 + g * 4];
                *(float4*)&out[(size_t)node * 64 + c8 * 8 + g * 4] = bv;
            }
        }
        return;
    }

    float ad = ad2[node];
    const uint32_t* rowp = h2p + 4 * c8;
    float acc[8] = {0.f, 0.f, 0.f, 0.f, 0.f, 0.f, 0.f, 0.f};
    float den = 0.f;

    int jw = r0 + eA;
    int sw0 = sorted_src[jw < r1 ? jw : r0] * H2W;
    int j1 = r0 + 8 + eA;
    int sw1 = sorted_src[j1 < r1 ? j1 : r0] * H2W;
    float av0 = __uint_as_float(h2p[sw0 + 32]);

    int of0A = __shfl(sw0, q,     32);
    int of1A = __shfl(sw0, q + 4, 32);
    uint4 hA0 = *(const uint4*)(rowp + of0A);
    uint4 hA1 = *(const uint4*)(rowp + of1A);

    for (int j = r0; j < r1; j += 8) {
        int jn = j + 16 + eA;
        int swn = sorted_src[jn < r1 ? jn : r0] * H2W;
        float avn = __uint_as_float(h2p[sw1 + 32]);

        int of0B = __shfl(sw1, q,     32);
        int of1B = __shfl(sw1, q + 4, 32);
        uint4 hB0 = *(const uint4*)(rowp + of0B);
        uint4 hB1 = *(const uint4*)(rowp + of1B);

        float ev = av0 + ad;
        ev = ev > 0.f ? ev : SLOPE * ev;
        float w = (j + eA) < r1 ? exp2f(ev) : 0.f;
        den += w;

        float wk0 = __shfl(w, q,     32);
        float wk1 = __shfl(w, q + 4, 32);
        fmix_lo(acc[0], hA0.x, wk0); fmix_hi(acc[1], hA0.x, wk0);
        fmix_lo(acc[2], hA0.y, wk0); fmix_hi(acc[3], hA0.y, wk0);
        fmix_lo(acc[4], hA0.z, wk0); fmix_hi(acc[5], hA0.z, wk0);
        fmix_lo(acc[6], hA0.w, wk0); fmix_hi(acc[7], hA0.w, wk0);
        fmix_lo(acc[0], hA1.x, wk1); fmix_hi(acc[1], hA1.x, wk1);
        fmix_lo(acc[2], hA1.y, wk1); fmix_hi(acc[3], hA1.y, wk1);
        fmix_lo(acc[4], hA1.z, wk1); fmix_hi(acc[5], hA1.z, wk1);
        fmix_lo(acc[6], hA1.w, wk1); fmix_hi(acc[7], hA1.w, wk1);

        hA0 = hB0; hA1 = hB1;
        sw0 = sw1; sw1 = swn; av0 = avn;
    }

    den += __shfl_xor(den, 1, 32);
    den += __shfl_xor(den, 2, 32);
    den += __shfl_xor(den, 4, 32);
    #pragma unroll
    for (int i = 0; i < 8; ++i) {
        acc[i] += __shfl_xor(acc[i], 8, 32);
        acc[i] += __shfl_xor(acc[i], 16, 32);
    }

    if (l < 8) {
        float inv = 1.0f / (den + EPSV);
        #pragma unroll
        for (int g = 0; g < 2; ++g) {
            float4 bv = *(const float4*)&b2[c8 * 8 + g * 4];
            *(float4*)&out[(size_t)node * 64 + c8 * 8 + g * 4] =
                make_float4(acc[g * 4 + 0] * inv + bv.x, acc[g * 4 + 1] * inv + bv.y,
                            acc[g * 4 + 2] * inv + bv.z, acc[g * 4 + 3] * inv + bv.w);
        }
    }
}

extern "C" void kernel_launch(void* const* d_in, const int* in_sizes, int n_in,
                              void* d_out, int out_size, void* d_ws, size_t ws_size,
                              hipStream_t stream)
{
    const int N = in_sizes[0] / 128;
    const int E = in_sizes[1] / 2;
    const int NB = (N + NPB2 - 1) / NPB2;        // 391 for N=100k (fits 512-wide scans)
    const int chunk = (E + NBLK - 1) / NBLK;
    const int gBlocks = (N + 127) / 128;

    const float* x        = (const float*)d_in[0];
    const int*   ei       = (const int*)  d_in[1];
    const float* W1       = (const float*)d_in[2];
    const float* att_src1 = (const float*)d_in[3];
    const float* att_dst1 = (const float*)d_in[4];
    const float* b1       = (const float*)d_in[5];
    const float* W2       = (const float*)d_in[6];
    const float* att_src2 = (const float*)d_in[7];
    const float* att_dst2 = (const float*)d_in[8];
    const float* b2       = (const float*)d_in[9];
    float* out = (float*)d_out;

    uint32_t* h1p  = (uint32_t*)d_ws;                 // N*72 words (reused as h2p N*36)
    float* hbuf    = (float*)(h1p + (size_t)N * H1W); // N*128
    float* ad1     = hbuf + (size_t)N * 128;          // N*8
    float* ad2     = ad1  + (size_t)N * 8;            // N
    int* row_start   = (int*)(ad2 + N);               // N+1
    int* bucket_base = row_start + (N + 1);           // NB+1
    int* btot        = bucket_base + (NB + 1);        // NB
    int* pbh         = btot + NB;                     // NB*NBLK
    int* sorted_src  = pbh + (size_t)NB * NBLK;       // E
    uint32_t* staging = (uint32_t*)(sorted_src + E);  // E
    uint32_t* h2p   = h1p;                            // alias: h1p dead after gather1

    // --- fused: bucket histogram (blocks 0..NBLK-1) + gemm1 (blocks NBLK..) ---
    fused_count_gemm1<<<NBLK + gBlocks, 256, 0, stream>>>(
        ei, pbh, E, NB, chunk, x, W1, att_src1, att_dst1, h1p, ad1, N, NBLK);

    // --- rest of the counting sort ---
    s_scanA<<<NB, 256, 0, stream>>>(pbh, btot, NB);
    s_scanC<<<NB, 256, 0, stream>>>(pbh, btot, bucket_base, NB, E);
    s_place<<<NBLK, 256, 0, stream>>>(ei, pbh, staging, E, NB, chunk);
    s_build<<<NB, 256, 0, stream>>>(staging, bucket_base, row_start, sorted_src, N, E, NB);

    // --- layer 1 gather ---
    gather1_kernel<<<(N + 3) / 4, 256, 0, stream>>>(row_start, sorted_src, ad1, h1p, b1, hbuf, N);

    // --- layer 2 ---
    gemm2_mfma<<<(N + 127) / 128, 256, 0, stream>>>(hbuf, W2, att_src2, att_dst2, h2p, ad2, N);
    gather2_kernel<<<(N + 7) / 8, 256, 0, stream>>>(row_start, sorted_src, ad2, h2p, b2, out, N);
}

// Round 16
// 249.110 us; speedup vs baseline: 1.0278x; 1.0278x over previous
//
#include <hip/hip_runtime.h>
#include <hip/hip_bf16.h>
#include <hip/hip_fp16.h>
#include <stdint.h>

#define SLOPE 0.2f
#define EPSV 1e-16f
#define LOG2E 1.44269504f
#define H1W 72    // h1p row stride in u32 words: 64 f16x2 words + 8 fp32 a_src (scaled)
#define H2W 36    // 32 f16x2 words + 1 fp32 a_src + 3 pad

#define NPB2  256   // nodes per bucket; bucket = dst >> 8
#define NBLK  512   // count/place blocks (pbh row width)

typedef __attribute__((ext_vector_type(8))) short bf16x8;
typedef __attribute__((ext_vector_type(4))) float f32x4;

static __device__ __forceinline__ uint32_t cvtpk(float a, float b) {   // bf16 pack (weights)
    uint32_t r;
    asm("v_cvt_pk_bf16_f32 %0, %1, %2" : "=v"(r) : "v"(a), "v"(b));
    return r;
}
static __device__ __forceinline__ float lof(uint32_t u) { return __uint_as_float(u << 16); }
static __device__ __forceinline__ float hif(uint32_t u) { return __uint_as_float(u & 0xffff0000u); }

static __device__ __forceinline__ uint32_t pkf16(float a, float b) {   // fp16 pack (RTZ)
    auto r = __builtin_amdgcn_cvt_pkrtz(a, b);
    return __builtin_bit_cast(uint32_t, r);
}

// acc += fp16(lo/hi half of h2) * w   — single VOP3P v_fma_mix_f32
static __device__ __forceinline__ void fmix_lo(float& acc, uint32_t h2, float w) {
    asm("v_fma_mix_f32 %0, %1, %2, %0 op_sel_hi:[1,0,0]" : "+v"(acc) : "v"(h2), "v"(w));
}
static __device__ __forceinline__ void fmix_hi(float& acc, uint32_t h2, float w) {
    asm("v_fma_mix_f32 %0, %1, %2, %0 op_sel:[1,0,0] op_sel_hi:[1,0,0]" : "+v"(acc) : "v"(h2), "v"(w));
}

union FragCvt { uint4 u; bf16x8 f; };

// ---------------- GEMM1 (MFMA split-precision): h1p = x @ W1, fused a_s/a_d ----------------
__global__ __launch_bounds__(256) void gemm1_mfma(
    const float* __restrict__ x,
    const uint32_t* __restrict__ wthi, const uint32_t* __restrict__ wtlo,
    const float* __restrict__ att_src, const float* __restrict__ att_dst,
    uint32_t* __restrict__ h1p, float* __restrict__ ad1, int N)
{
    __shared__ uint32_t lds[2][128 * 36];
    const int t = threadIdx.x;
    const int w = t >> 6, l = t & 63;
    const int cl = l & 15, rg = l >> 4;
    const int rowbase = blockIdx.x * 128 + w * 32;

    f32x4 zero = {0.f, 0.f, 0.f, 0.f};
    f32x4 acc[2][8];
    #pragma unroll
    for (int rt = 0; rt < 2; ++rt)
        #pragma unroll
        for (int tl = 0; tl < 8; ++tl) acc[rt][tl] = zero;

    for (int kh = 0; kh < 2; ++kh) {
        if (kh) __syncthreads();
        for (int i = t; i < 1024; i += 256) {
            int col = i >> 3, q = i & 7;
            *(uint4*)&lds[0][col * 36 + q * 4] = *(const uint4*)&wthi[col * 64 + kh * 32 + q * 4];
            *(uint4*)&lds[1][col * 36 + q * 4] = *(const uint4*)&wtlo[col * 64 + kh * 32 + q * 4];
        }
        __syncthreads();
        #pragma unroll
        for (int ks = 0; ks < 2; ++ks) {
            const int kg = kh * 64 + ks * 32 + rg * 8;
            bf16x8 ahi[2], alo[2];
            #pragma unroll
            for (int rt = 0; rt < 2; ++rt) {
                int row = rowbase + rt * 16 + cl;
                row = min(row, N - 1);
                const float* xr = x + (size_t)row * 128 + kg;
                float4 v0 = *(const float4*)xr;
                float4 v1 = *(const float4*)(xr + 4);
                uint32_t h0 = cvtpk(v0.x, v0.y), h1 = cvtpk(v0.z, v0.w);
                uint32_t h2 = cvtpk(v1.x, v1.y), h3 = cvtpk(v1.z, v1.w);
                uint32_t l0 = cvtpk(v0.x - lof(h0), v0.y - hif(h0));
                uint32_t l1 = cvtpk(v0.z - lof(h1), v0.w - hif(h1));
                uint32_t l2 = cvtpk(v1.x - lof(h2), v1.y - hif(h2));
                uint32_t l3 = cvtpk(v1.z - lof(h3), v1.w - hif(h3));
                FragCvt ch, clo;
                ch.u  = make_uint4(h0, h1, h2, h3);
                clo.u = make_uint4(l0, l1, l2, l3);
                ahi[rt] = ch.f; alo[rt] = clo.f;
            }
            #pragma unroll
            for (int tl = 0; tl < 8; ++tl) {
                const int off = (tl * 16 + cl) * 36 + ks * 16 + rg * 4;
                bf16x8 bhi = *(const bf16x8*)&lds[0][off];
                bf16x8 blo = *(const bf16x8*)&lds[1][off];
                #pragma unroll
                for (int rt = 0; rt < 2; ++rt) {
                    acc[rt][tl] = __builtin_amdgcn_mfma_f32_16x16x32_bf16(alo[rt], bhi, acc[rt][tl], 0, 0, 0);
                    acc[rt][tl] = __builtin_amdgcn_mfma_f32_16x16x32_bf16(ahi[rt], blo, acc[rt][tl], 0, 0, 0);
                    acc[rt][tl] = __builtin_amdgcn_mfma_f32_16x16x32_bf16(ahi[rt], bhi, acc[rt][tl], 0, 0, 0);
                }
            }
        }
    }

    // epilogue: fp16 pack; a_s/a_d dots pre-scaled by log2e (exp2-direct downstream)
    #pragma unroll
    for (int rt = 0; rt < 2; ++rt) {
        const int rowb = rowbase + rt * 16 + rg * 4;
        #pragma unroll
        for (int tl = 0; tl < 8; ++tl) {
            f32x4 a = acc[rt][tl];
            float as_ = att_src[tl * 16 + cl] * LOG2E, ad_ = att_dst[tl * 16 + cl] * LOG2E;
            float s0 = a.x * as_, s1 = a.y * as_, s2 = a.z * as_, s3 = a.w * as_;
            float d0 = a.x * ad_, d1 = a.y * ad_, d2 = a.z * ad_, d3 = a.w * ad_;
            #pragma unroll
            for (int off = 1; off < 16; off <<= 1) {
                s0 += __shfl_xor(s0, off); s1 += __shfl_xor(s1, off);
                s2 += __shfl_xor(s2, off); s3 += __shfl_xor(s3, off);
                d0 += __shfl_xor(d0, off); d1 += __shfl_xor(d1, off);
                d2 += __shfl_xor(d2, off); d3 += __shfl_xor(d3, off);
            }
            float av[4] = {a.x, a.y, a.z, a.w};
            #pragma unroll
            for (int r = 0; r < 4; ++r) {
                float partner = __shfl_xor(av[r], 1);
                if (!(cl & 1)) {
                    int row = rowb + r;
                    if (row < N)
                        h1p[(size_t)row * H1W + tl * 8 + (cl >> 1)] = pkf16(av[r], partner);
                }
            }
            if (cl == 0) {
                float sv[4] = {s0, s1, s2, s3}, dv[4] = {d0, d1, d2, d3};
                #pragma unroll
                for (int r = 0; r < 4; ++r) {
                    int row = rowb + r;
                    if (row < N) {
                        h1p[(size_t)row * H1W + 64 + tl] = __float_as_uint(sv[r]);
                        ad1[row * 8 + tl] = dv[r];
                    }
                }
            }
        }
    }
}

// ---------------- GEMM2 (MFMA split-precision): h2p = hbuf @ W2, fused a_s2/a_d2 ----------------
__global__ __launch_bounds__(256) void gemm2_mfma(
    const float* __restrict__ h,
    const uint32_t* __restrict__ wthi, const uint32_t* __restrict__ wtlo,
    const float* __restrict__ att_src, const float* __restrict__ att_dst,
    uint32_t* __restrict__ h2p, float* __restrict__ ad2, int N)
{
    __shared__ uint32_t lds[2][64 * 36];
    const int t = threadIdx.x;
    const int w = t >> 6, l = t & 63;
    const int cl = l & 15, rg = l >> 4;
    const int rowbase = blockIdx.x * 128 + w * 32;

    f32x4 zero = {0.f, 0.f, 0.f, 0.f};
    f32x4 acc[2][4];
    #pragma unroll
    for (int rt = 0; rt < 2; ++rt)
        #pragma unroll
        for (int tl = 0; tl < 4; ++tl) acc[rt][tl] = zero;

    for (int kh = 0; kh < 2; ++kh) {
        if (kh) __syncthreads();
        for (int i = t; i < 512; i += 256) {
            int col = i >> 3, q = i & 7;
            *(uint4*)&lds[0][col * 36 + q * 4] = *(const uint4*)&wthi[col * 64 + kh * 32 + q * 4];
            *(uint4*)&lds[1][col * 36 + q * 4] = *(const uint4*)&wtlo[col * 64 + kh * 32 + q * 4];
        }
        __syncthreads();
        #pragma unroll
        for (int ks = 0; ks < 2; ++ks) {
            const int kg = kh * 64 + ks * 32 + rg * 8;
            bf16x8 ahi[2], alo[2];
            #pragma unroll
            for (int rt = 0; rt < 2; ++rt) {
                int row = rowbase + rt * 16 + cl;
                row = min(row, N - 1);
                const float* xr = h + (size_t)row * 128 + kg;
                float4 v0 = *(const float4*)xr;
                float4 v1 = *(const float4*)(xr + 4);
                uint32_t h0 = cvtpk(v0.x, v0.y), h1 = cvtpk(v0.z, v0.w);
                uint32_t h2 = cvtpk(v1.x, v1.y), h3 = cvtpk(v1.z, v1.w);
                uint32_t l0 = cvtpk(v0.x - lof(h0), v0.y - hif(h0));
                uint32_t l1 = cvtpk(v0.z - lof(h1), v0.w - hif(h1));
                uint32_t l2 = cvtpk(v1.x - lof(h2), v1.y - hif(h2));
                uint32_t l3 = cvtpk(v1.z - lof(h3), v1.w - hif(h3));
                FragCvt ch, clo;
                ch.u  = make_uint4(h0, h1, h2, h3);
                clo.u = make_uint4(l0, l1, l2, l3);
                ahi[rt] = ch.f; alo[rt] = clo.f;
            }
            #pragma unroll
            for (int tl = 0; tl < 4; ++tl) {
                const int off = (tl * 16 + cl) * 36 + ks * 16 + rg * 4;
                bf16x8 bhi = *(const bf16x8*)&lds[0][off];
                bf16x8 blo = *(const bf16x8*)&lds[1][off];
                #pragma unroll
                for (int rt = 0; rt < 2; ++rt) {
                    acc[rt][tl] = __builtin_amdgcn_mfma_f32_16x16x32_bf16(alo[rt], bhi, acc[rt][tl], 0, 0, 0);
                    acc[rt][tl] = __builtin_amdgcn_mfma_f32_16x16x32_bf16(ahi[rt], blo, acc[rt][tl], 0, 0, 0);
                    acc[rt][tl] = __builtin_amdgcn_mfma_f32_16x16x32_bf16(ahi[rt], bhi, acc[rt][tl], 0, 0, 0);
                }
            }
        }
    }

    #pragma unroll
    for (int rt = 0; rt < 2; ++rt) {
        const int rowb = rowbase + rt * 16 + rg * 4;
        float s0 = 0.f, s1 = 0.f, s2 = 0.f, s3 = 0.f;
        float d0 = 0.f, d1 = 0.f, d2 = 0.f, d3 = 0.f;
        #pragma unroll
        for (int tl = 0; tl < 4; ++tl) {
            f32x4 a = acc[rt][tl];
            float as_ = att_src[tl * 16 + cl] * LOG2E, ad_ = att_dst[tl * 16 + cl] * LOG2E;
            s0 += a.x * as_; s1 += a.y * as_; s2 += a.z * as_; s3 += a.w * as_;
            d0 += a.x * ad_; d1 += a.y * ad_; d2 += a.z * ad_; d3 += a.w * ad_;
            float av[4] = {a.x, a.y, a.z, a.w};
            #pragma unroll
            for (int r = 0; r < 4; ++r) {
                float partner = __shfl_xor(av[r], 1);
                if (!(cl & 1)) {
                    int row = rowb + r;
                    if (row < N)
                        h2p[(size_t)row * H2W + tl * 8 + (cl >> 1)] = pkf16(av[r], partner);
                }
            }
        }
        #pragma unroll
        for (int off = 1; off < 16; off <<= 1) {
            s0 += __shfl_xor(s0, off); s1 += __shfl_xor(s1, off);
            s2 += __shfl_xor(s2, off); s3 += __shfl_xor(s3, off);
            d0 += __shfl_xor(d0, off); d1 += __shfl_xor(d1, off);
            d2 += __shfl_xor(d2, off); d3 += __shfl_xor(d3, off);
        }
        if (cl == 0) {
            float sv[4] = {s0, s1, s2, s3}, dv[4] = {d0, d1, d2, d3};
            #pragma unroll
            for (int r = 0; r < 4; ++r) {
                int row = rowb + r;
                if (row < N) {
                    h2p[(size_t)row * H2W + 32] = __float_as_uint(sv[r]);
                    ad2[row] = dv[r];
                }
            }
        }
    }
}

// ================= bucket counting sort by dst (parallel, no global atomics) =================
// s_count: grid NBLK+2; blocks >= NBLK do weight prep (independent work, saves a launch)
__global__ __launch_bounds__(256) void s_count(
    const int* __restrict__ ei, int* __restrict__ pbh, int E, int NB, int chunk,
    const float* __restrict__ W1, const float* __restrict__ W2,
    uint32_t* __restrict__ wt1hi, uint32_t* __restrict__ wt1lo,
    uint32_t* __restrict__ wt2hi, uint32_t* __restrict__ wt2lo)
{
    int t = threadIdx.x;
    if (blockIdx.x >= NBLK) {
        if (blockIdx.x == NBLK) {
            for (int i = t; i < 128 * 64; i += 256) {
                int n = i >> 6, kp = i & 63;
                float w0 = W1[(2 * kp) * 128 + n], w1 = W1[(2 * kp + 1) * 128 + n];
                uint32_t h = cvtpk(w0, w1);
                wt1hi[n * 64 + kp] = h;
                wt1lo[n * 64 + kp] = cvtpk(w0 - lof(h), w1 - hif(h));
            }
        } else {
            for (int i = t; i < 64 * 64; i += 256) {
                int n = i >> 6, kp = i & 63;
                float w0 = W2[(2 * kp) * 64 + n], w1 = W2[(2 * kp + 1) * 64 + n];
                uint32_t h = cvtpk(w0, w1);
                wt2hi[n * 64 + kp] = h;
                wt2lo[n * 64 + kp] = cvtpk(w0 - lof(h), w1 - hif(h));
            }
        }
        return;
    }
    __shared__ int hist[512];
    hist[t] = 0; hist[t + 256] = 0;
    __syncthreads();
    int e0 = blockIdx.x * chunk, e1 = min(E, e0 + chunk);
    for (int e = e0 + t; e < e1; e += 256)
        atomicAdd(&hist[ei[E + e] >> 8], 1);
    __syncthreads();
    for (int b = t; b < NB; b += 256)
        pbh[(size_t)b * NBLK + blockIdx.x] = hist[b];   // bucket-major
}

// s_scanA: grid NB x 256; bucket totals
__global__ __launch_bounds__(256) void s_scanA(
    const int* __restrict__ pbh, int* __restrict__ btot, int NB)
{
    __shared__ int red[256];
    int b = blockIdx.x, t = threadIdx.x;
    int s = pbh[(size_t)b * NBLK + t] + pbh[(size_t)b * NBLK + 256 + t];
    red[t] = s; __syncthreads();
    for (int off = 128; off; off >>= 1) {
        if (t < off) red[t] += red[t + off];
        __syncthreads();
    }
    if (t == 0) btot[b] = red[0];
}

// s_scanC: grid NB x 256; each block scans btot (redundantly) for its base, then
// scans its pbh row -> absolute run bases; writes bucket_base.
__global__ __launch_bounds__(256) void s_scanC(
    int* __restrict__ pbh, const int* __restrict__ btot,
    int* __restrict__ bucket_base, int NB, int E)
{
    __shared__ int ps[256];
    __shared__ int exv[512];
    int b = blockIdx.x, t = threadIdx.x;
    // pass 1: exclusive scan of btot (padded to 512)
    int v0 = (2 * t     < NB) ? btot[2 * t]     : 0;
    int v1 = (2 * t + 1 < NB) ? btot[2 * t + 1] : 0;
    int p = v0 + v1;
    ps[t] = p; __syncthreads();
    for (int off = 1; off < 256; off <<= 1) {
        int add = (t >= off) ? ps[t - off] : 0;
        __syncthreads();
        ps[t] += add;
        __syncthreads();
    }
    int pex = ps[t] - p;
    exv[2 * t] = pex; exv[2 * t + 1] = pex + v0;
    __syncthreads();
    int base = exv[b];
    if (t == 0) {
        bucket_base[b] = base;
        if (b == NB - 1) bucket_base[NB] = E;
    }
    __syncthreads();
    // pass 2: per-bucket row exclusive scan (512 wide, pair trick)
    int w0 = pbh[(size_t)b * NBLK + 2 * t], w1 = pbh[(size_t)b * NBLK + 2 * t + 1];
    int pp = w0 + w1;
    ps[t] = pp; __syncthreads();
    for (int off = 1; off < 256; off <<= 1) {
        int add = (t >= off) ? ps[t - off] : 0;
        __syncthreads();
        ps[t] += add;
        __syncthreads();
    }
    int ex = base + ps[t] - pp;
    pbh[(size_t)b * NBLK + 2 * t]     = ex;
    pbh[(size_t)b * NBLK + 2 * t + 1] = ex + w0;
}

// s_place: grid NBLK x 256; place edges into bucket regions (packed src|dst_local)
__global__ __launch_bounds__(256) void s_place(
    const int* __restrict__ ei, const int* __restrict__ pbh,
    uint32_t* __restrict__ staging, int E, int NB, int chunk)
{
    __shared__ int lcur[512];
    int t = threadIdx.x;
    if (t < NB)       lcur[t]       = pbh[(size_t)t * NBLK + blockIdx.x];
    if (t + 256 < NB) lcur[t + 256] = pbh[(size_t)(t + 256) * NBLK + blockIdx.x];
    __syncthreads();
    int e0 = blockIdx.x * chunk, e1 = min(E, e0 + chunk);
    for (int e = e0 + t; e < e1; e += 256) {
        int s = ei[e], d = ei[E + e];
        int p = atomicAdd(&lcur[d >> 8], 1);     // LDS atomic
        staging[p] = ((uint32_t)s << 8) | (uint32_t)(d & 255);
    }
}

// s_build: grid NB x 256; per-bucket CSR build (row_start + sorted_src)
__global__ __launch_bounds__(256) void s_build(
    const uint32_t* __restrict__ staging, const int* __restrict__ bucket_base,
    int* __restrict__ row_start, int* __restrict__ sorted_src, int N, int E, int NB)
{
    __shared__ int cnt[256];
    __shared__ int ofs[256];
    __shared__ int ps[256];
    int b = blockIdx.x, t = threadIdx.x;
    int base = bucket_base[b], end = bucket_base[b + 1];
    cnt[t] = 0;
    __syncthreads();
    for (int i = base + t; i < end; i += 256)
        atomicAdd(&cnt[staging[i] & 255], 1);
    __syncthreads();
    int c = cnt[t];
    ps[t] = c; __syncthreads();
    for (int off = 1; off < 256; off <<= 1) {
        int add = (t >= off) ? ps[t - off] : 0;
        __syncthreads();
        ps[t] += add;
        __syncthreads();
    }
    int ex = ps[t] - c;
    ofs[t] = ex;
    int node = b * NPB2 + t;
    if (node < N) row_start[node] = base + ex;
    if (b == NB - 1 && t == 0) row_start[N] = E;
    __syncthreads();
    for (int i = base + t; i < end; i += 256) {
        uint32_t v = staging[i];
        int pos = base + atomicAdd(&ofs[v & 255], 1);   // LDS atomic
        sorted_src[pos] = (int)(v >> 8);
    }
}

// ---------------- gather layer 1: 64 lanes/node, fp16 rows, 16B gathers, fma_mix,
// row loads software-pipelined one 8-edge group ahead ----------------
__global__ __launch_bounds__(256) void gather1_kernel(
    const int* __restrict__ row_start, const int* __restrict__ sorted_src,
    const float* __restrict__ ad1, const uint32_t* __restrict__ h1p,
    const float* __restrict__ b1, float* __restrict__ hbuf, int N)
{
    int node = blockIdx.x * 4 + (threadIdx.x >> 6);
    if (node >= N) return;
    const int l  = threadIdx.x & 63;
    const int wh = l & 7;          // weight-duty head
    const int eA = l >> 3;         // weight-duty edge slot (0..7)
    const int c8 = l & 15;         // channel-octet: channels 8*c8..+7
    const int q  = l >> 4;         // phase-B quarter (0..3)
    const int hB = c8 >> 1;        // fma-duty head

    int r0 = row_start[node], r1 = row_start[node + 1];

    if (r0 == r1) {                // isolated node: out = elu(b1)
        if (l < 16) {
            #pragma unroll
            for (int g = 0; g < 2; ++g) {
                float4 bv = *(const float4*)&b1[c8 * 8 + g * 4];
                bv.x = bv.x > 0.f ? bv.x : expm1f(bv.x);
                bv.y = bv.y > 0.f ? bv.y : expm1f(bv.y);
                bv.z = bv.z > 0.f ? bv.z : expm1f(bv.z);
                bv.w = bv.w > 0.f ? bv.w : expm1f(bv.w);
                *(float4*)&hbuf[(size_t)node * 128 + c8 * 8 + g * 4] = bv;
            }
        }
        return;
    }

    float adw = ad1[node * 8 + wh];
    const uint32_t* rowp = h1p + 4 * c8;
    float acc[8] = {0.f, 0.f, 0.f, 0.f, 0.f, 0.f, 0.f, 0.f};
    float den = 0.f;

    int jw = r0 + eA;
    int sw0 = sorted_src[jw < r1 ? jw : r0] * H1W;
    int j1 = r0 + 8 + eA;
    int sw1 = sorted_src[j1 < r1 ? j1 : r0] * H1W;
    float av0 = __uint_as_float(h1p[sw0 + 64 + wh]);

    // preload group 0's channel rows
    int of0A = __shfl(sw0,  q      * 8, 64);
    int of1A = __shfl(sw0, (q + 4) * 8, 64);
    uint4 hA0 = *(const uint4*)(rowp + of0A);
    uint4 hA1 = *(const uint4*)(rowp + of1A);

    for (int j = r0; j < r1; j += 8) {
        int jn = j + 16 + eA;
        int swn = sorted_src[jn < r1 ? jn : r0] * H1W;
        float avn = __uint_as_float(h1p[sw1 + 64 + wh]);

        // issue next group's channel-row loads (offsets known from sw1)
        int of0B = __shfl(sw1,  q      * 8, 64);
        int of1B = __shfl(sw1, (q + 4) * 8, 64);
        uint4 hB0 = *(const uint4*)(rowp + of0B);
        uint4 hB1 = *(const uint4*)(rowp + of1B);

        float ev = av0 + adw;
        ev = ev > 0.f ? ev : SLOPE * ev;
        float w = (j + eA) < r1 ? exp2f(ev) : 0.f;
        den += w;

        float wk0 = __shfl(w,  q      * 8 + hB, 64);
        float wk1 = __shfl(w, (q + 4) * 8 + hB, 64);
        fmix_lo(acc[0], hA0.x, wk0); fmix_hi(acc[1], hA0.x, wk0);
        fmix_lo(acc[2], hA0.y, wk0); fmix_hi(acc[3], hA0.y, wk0);
        fmix_lo(acc[4], hA0.z, wk0); fmix_hi(acc[5], hA0.z, wk0);
        fmix_lo(acc[6], hA0.w, wk0); fmix_hi(acc[7], hA0.w, wk0);
        fmix_lo(acc[0], hA1.x, wk1); fmix_hi(acc[1], hA1.x, wk1);
        fmix_lo(acc[2], hA1.y, wk1); fmix_hi(acc[3], hA1.y, wk1);
        fmix_lo(acc[4], hA1.z, wk1); fmix_hi(acc[5], hA1.z, wk1);
        fmix_lo(acc[6], hA1.w, wk1); fmix_hi(acc[7], hA1.w, wk1);

        hA0 = hB0; hA1 = hB1;
        sw0 = sw1; sw1 = swn; av0 = avn;
    }

    den += __shfl_xor(den, 8, 64);
    den += __shfl_xor(den, 16, 64);
    den += __shfl_xor(den, 32, 64);
    float dB = __shfl(den, hB, 64);

    #pragma unroll
    for (int i = 0; i < 8; ++i) {
        acc[i] += __shfl_xor(acc[i], 16, 64);
        acc[i] += __shfl_xor(acc[i], 32, 64);
    }

    if (l < 16) {
        float inv = 1.0f / (dB + EPSV);
        #pragma unroll
        for (int g = 0; g < 2; ++g) {
            float4 bv = *(const float4*)&b1[c8 * 8 + g * 4];
            float v0 = acc[g * 4 + 0] * inv + bv.x;
            float v1 = acc[g * 4 + 1] * inv + bv.y;
            float v2 = acc[g * 4 + 2] * inv + bv.z;
            float v3 = acc[g * 4 + 3] * inv + bv.w;
            v0 = v0 > 0.f ? v0 : expm1f(v0);
            v1 = v1 > 0.f ? v1 : expm1f(v1);
            v2 = v2 > 0.f ? v2 : expm1f(v2);
            v3 = v3 > 0.f ? v3 : expm1f(v3);
            *(float4*)&hbuf[(size_t)node * 128 + c8 * 8 + g * 4] = make_float4(v0, v1, v2, v3);
        }
    }
}

// ---------------- gather layer 2: 32 lanes/node, fp16 rows, 16B gathers, fma_mix,
// row loads pipelined one group ahead ----------------
__global__ __launch_bounds__(256) void gather2_kernel(
    const int* __restrict__ row_start, const int* __restrict__ sorted_src,
    const float* __restrict__ ad2, const uint32_t* __restrict__ h2p,
    const float* __restrict__ b2, float* __restrict__ out, int N)
{
    int node = blockIdx.x * 8 + (threadIdx.x >> 5);
    if (node >= N) return;
    const int l  = threadIdx.x & 31;
    const int eA = l & 7;          // weight-duty edge slot (4x redundant)
    const int c8 = l & 7;          // channel-octet: channels 8*c8..+7
    const int q  = l >> 3;         // phase-B quarter (0..3)

    int r0 = row_start[node], r1 = row_start[node + 1];

    if (r0 == r1) {
        if (l < 8) {
            #pragma unroll
            for (int g = 0; g < 2; ++g) {
                float4 bv = *(const float4*)&b2[c8 * 8 + g * 4];
                *(float4*)&out[(size_t)node * 64 + c8 * 8 + g * 4] = bv;
            }
        }
        return;
    }

    float ad = ad2[node];
    const uint32_t* rowp = h2p + 4 * c8;
    float acc[8] = {0.f, 0.f, 0.f, 0.f, 0.f, 0.f, 0.f, 0.f};
    float den = 0.f;

    int jw = r0 + eA;
    int sw0 = sorted_src[jw < r1 ? jw : r0] * H2W;
    int j1 = r0 + 8 + eA;
    int sw1 = sorted_src[j1 < r1 ? j1 : r0] * H2W;
    float av0 = __uint_as_float(h2p[sw0 + 32]);

    int of0A = __shfl(sw0, q,     32);
    int of1A = __shfl(sw0, q + 4, 32);
    uint4 hA0 = *(const uint4*)(rowp + of0A);
    uint4 hA1 = *(const uint4*)(rowp + of1A);

    for (int j = r0; j < r1; j += 8) {
        int jn = j + 16 + eA;
        int swn = sorted_src[jn < r1 ? jn : r0] * H2W;
        float avn = __uint_as_float(h2p[sw1 + 32]);

        int of0B = __shfl(sw1, q,     32);
        int of1B = __shfl(sw1, q + 4, 32);
        uint4 hB0 = *(const uint4*)(rowp + of0B);
        uint4 hB1 = *(const uint4*)(rowp + of1B);

        float ev = av0 + ad;
        ev = ev > 0.f ? ev : SLOPE * ev;
        float w = (j + eA) < r1 ? exp2f(ev) : 0.f;
        den += w;

        float wk0 = __shfl(w, q,     32);
        float wk1 = __shfl(w, q + 4, 32);
        fmix_lo(acc[0], hA0.x, wk0); fmix_hi(acc[1], hA0.x, wk0);
        fmix_lo(acc[2], hA0.y, wk0); fmix_hi(acc[3], hA0.y, wk0);
        fmix_lo(acc[4], hA0.z, wk0); fmix_hi(acc[5], hA0.z, wk0);
        fmix_lo(acc[6], hA0.w, wk0); fmix_hi(acc[7], hA0.w, wk0);
        fmix_lo(acc[0], hA1.x, wk1); fmix_hi(acc[1], hA1.x, wk1);
        fmix_lo(acc[2], hA1.y, wk1); fmix_hi(acc[3], hA1.y, wk1);
        fmix_lo(acc[4], hA1.z, wk1); fmix_hi(acc[5], hA1.z, wk1);
        fmix_lo(acc[6], hA1.w, wk1); fmix_hi(acc[7], hA1.w, wk1);

        hA0 = hB0; hA1 = hB1;
        sw0 = sw1; sw1 = swn; av0 = avn;
    }

    den += __shfl_xor(den, 1, 32);
    den += __shfl_xor(den, 2, 32);
    den += __shfl_xor(den, 4, 32);
    #pragma unroll
    for (int i = 0; i < 8; ++i) {
        acc[i] += __shfl_xor(acc[i], 8, 32);
        acc[i] += __shfl_xor(acc[i], 16, 32);
    }

    if (l < 8) {
        float inv = 1.0f / (den + EPSV);
        #pragma unroll
        for (int g = 0; g < 2; ++g) {
            float4 bv = *(const float4*)&b2[c8 * 8 + g * 4];
            *(float4*)&out[(size_t)node * 64 + c8 * 8 + g * 4] =
                make_float4(acc[g * 4 + 0] * inv + bv.x, acc[g * 4 + 1] * inv + bv.y,
                            acc[g * 4 + 2] * inv + bv.z, acc[g * 4 + 3] * inv + bv.w);
        }
    }
}

extern "C" void kernel_launch(void* const* d_in, const int* in_sizes, int n_in,
                              void* d_out, int out_size, void* d_ws, size_t ws_size,
                              hipStream_t stream)
{
    const int N = in_sizes[0] / 128;
    const int E = in_sizes[1] / 2;
    const int NB = (N + NPB2 - 1) / NPB2;        // 391 for N=100k (fits 512-wide scans)
    const int chunk = (E + NBLK - 1) / NBLK;

    const float* x        = (const float*)d_in[0];
    const int*   ei       = (const int*)  d_in[1];
    const float* W1       = (const float*)d_in[2];
    const float* att_src1 = (const float*)d_in[3];
    const float* att_dst1 = (const float*)d_in[4];
    const float* b1       = (const float*)d_in[5];
    const float* W2       = (const float*)d_in[6];
    const float* att_src2 = (const float*)d_in[7];
    const float* att_dst2 = (const float*)d_in[8];
    const float* b2       = (const float*)d_in[9];
    float* out = (float*)d_out;

    uint32_t* h1p  = (uint32_t*)d_ws;                 // N*72 words (reused as h2p N*36)
    float* hbuf    = (float*)(h1p + (size_t)N * H1W); // N*128
    float* ad1     = hbuf + (size_t)N * 128;          // N*8
    float* ad2     = ad1  + (size_t)N * 8;            // N
    int* row_start   = (int*)(ad2 + N);               // N+1
    int* bucket_base = row_start + (N + 1);           // NB+1
    int* btot        = bucket_base + (NB + 1);        // NB
    int* pbh         = btot + NB;                     // NB*NBLK
    int* sorted_src  = pbh + (size_t)NB * NBLK;       // E
    uint32_t* staging = (uint32_t*)(sorted_src + E);  // E
    uint32_t* wt1hi = staging + E;                    // 8192
    uint32_t* wt1lo = wt1hi + 128 * 64;               // 8192
    uint32_t* wt2hi = wt1lo + 128 * 64;               // 4096
    uint32_t* wt2lo = wt2hi + 64 * 64;                // 4096
    uint32_t* h2p   = h1p;                            // alias: h1p dead after gather1

    // --- bucket counting sort by dst (parallel; no global atomics); prep fused in ---
    s_count<<<NBLK + 2, 256, 0, stream>>>(ei, pbh, E, NB, chunk,
                                          W1, W2, wt1hi, wt1lo, wt2hi, wt2lo);
    s_scanA<<<NB, 256, 0, stream>>>(pbh, btot, NB);
    s_scanC<<<NB, 256, 0, stream>>>(pbh, btot, bucket_base, NB, E);
    s_place<<<NBLK, 256, 0, stream>>>(ei, pbh, staging, E, NB, chunk);
    s_build<<<NB, 256, 0, stream>>>(staging, bucket_base, row_start, sorted_src, N, E, NB);

    // --- layer 1 ---
    gemm1_mfma<<<(N + 127) / 128, 256, 0, stream>>>(x, wt1hi, wt1lo, att_src1, att_dst1, h1p, ad1, N);
    gather1_kernel<<<(N + 3) / 4, 256, 0, stream>>>(row_start, sorted_src, ad1, h1p, b1, hbuf, N);

    // --- layer 2 ---
    gemm2_mfma<<<(N + 127) / 128, 256, 0, stream>>>(hbuf, wt2hi, wt2lo, att_src2, att_dst2, h2p, ad2, N);
    gather2_kernel<<<(N + 7) / 8, 256, 0, stream>>>(row_start, sorted_src, ad2, h2p, b2, out, N);
}